// Round 1
// baseline (202.467 us; speedup 1.0000x reference)
//
#include <hip/hip_runtime.h>

// AdditiveAttention: b=4, n_q=64, s=1024, Q_DIM=K_DIM=HID=VDIM=512, all f32.
// Pipeline: q_proj GEMM, k_proj GEMM(+bias), fused tanh-scores, softmax, AV GEMM.

static constexpr int BATCH = 4;
static constexpr int NQ    = 64;
static constexpr int SLEN  = 1024;
static constexpr int DIM   = 512;

__device__ __forceinline__ float fast_exp2(float x) {
#if __has_builtin(__builtin_amdgcn_exp2f)
    return __builtin_amdgcn_exp2f(x);
#else
    return exp2f(x);
#endif
}

__device__ __forceinline__ float fast_rcp(float x) {
#if __has_builtin(__builtin_amdgcn_rcpf)
    return __builtin_amdgcn_rcpf(x);
#else
    return 1.0f / x;
#endif
}

// tanh(x) = 1 - 2/(1+e^{2x});  e^{2x} = 2^{x*2*log2(e)}
// x->+inf: exp2->inf, rcp->0, result 1.  x->-inf: exp2->0, result -1.
__device__ __forceinline__ float tanh_fast(float x) {
    float e = fast_exp2(x * 2.885390081777927f);
    return 1.0f - 2.0f * fast_rcp(1.0f + e);
}

// C[M x 512] = A[M x 512] * W[:, col_off:col_off+512]^T (+ bias)
// W is (512 x 1024) row-major. Tile 64x64, K-chunk 32, 4x4 micro-tile.
__global__ __launch_bounds__(256) void proj_gemm(
    const float* __restrict__ A, const float* __restrict__ W,
    const float* __restrict__ bias, float* __restrict__ C, int col_off)
{
    __shared__ __align__(16) float As[32][68];
    __shared__ __align__(16) float Bs[32][68];
    const int t  = threadIdx.x;
    const int mb = blockIdx.x * 64;
    const int nb = blockIdx.y * 64;
    const int tx = t & 15, ty = t >> 4;
    float acc[4][4] = {};
    for (int kc = 0; kc < DIM; kc += 32) {
#pragma unroll
        for (int r = 0; r < 2; ++r) {
            int idx = t + r * 256;
            int m   = idx >> 3;
            int k4  = (idx & 7) << 2;
            float4 av = *(const float4*)(A + (size_t)(mb + m) * DIM + kc + k4);
            As[k4 + 0][m] = av.x; As[k4 + 1][m] = av.y;
            As[k4 + 2][m] = av.z; As[k4 + 3][m] = av.w;
            float4 wv = *(const float4*)(W + (size_t)(nb + m) * 1024 + col_off + kc + k4);
            Bs[k4 + 0][m] = wv.x; Bs[k4 + 1][m] = wv.y;
            Bs[k4 + 2][m] = wv.z; Bs[k4 + 3][m] = wv.w;
        }
        __syncthreads();
#pragma unroll
        for (int k = 0; k < 32; ++k) {
            float4 a  = *(const float4*)&As[k][ty << 2];
            float4 bv = *(const float4*)&Bs[k][tx << 2];
            float am[4] = {a.x, a.y, a.z, a.w};
            float bn[4] = {bv.x, bv.y, bv.z, bv.w};
#pragma unroll
            for (int i = 0; i < 4; ++i)
#pragma unroll
                for (int j = 0; j < 4; ++j)
                    acc[i][j] = fmaf(am[i], bn[j], acc[i][j]);
        }
        __syncthreads();
    }
#pragma unroll
    for (int i = 0; i < 4; ++i) {
        int row = mb + (ty << 2) + i;
        float4 o;
        int col = nb + (tx << 2);
        o.x = acc[i][0]; o.y = acc[i][1]; o.z = acc[i][2]; o.w = acc[i][3];
        if (bias) {
            float4 bb = *(const float4*)(bias + col);
            o.x += bb.x; o.y += bb.y; o.z += bb.z; o.w += bb.w;
        }
        *(float4*)(C + (size_t)row * DIM + col) = o;
    }
}

// scores[b,q,s] = sum_h w2[h] * tanh(qp[b*64+q][h] + kp[b*1024+s][h])
// Block: 256 thr, tile 16q x 32s; thread handles (tq, ts) and (tq, ts+16).
// Grid: (st=32, qt=4, b=4)
__global__ __launch_bounds__(256) void scores_kernel(
    const float* __restrict__ qp, const float* __restrict__ kp,
    const float* __restrict__ w2, float* __restrict__ scores)
{
    __shared__ __align__(16) float qs[16][68];
    __shared__ __align__(16) float ks[32][68];
    __shared__ __align__(16) float ws2[512];
    const int t     = threadIdx.x;
    const int sb    = blockIdx.x * 32;
    const int qrow0 = blockIdx.z * 64 + blockIdx.y * 16;
    const int krow0 = blockIdx.z * 1024 + sb;

    if (t < 128) *(float4*)&ws2[t << 2] = *(const float4*)(w2 + (t << 2));

    const int tq = t >> 4;
    const int ts = t & 15;
    float acc0 = 0.f, acc1 = 0.f;

    for (int kc = 0; kc < DIM; kc += 64) {
        {
            int r = t >> 4, g = (t & 15) << 2;
            *(float4*)&qs[r][g] = *(const float4*)(qp + (size_t)(qrow0 + r) * DIM + kc + g);
        }
#pragma unroll
        for (int rr = 0; rr < 2; ++rr) {
            int idx = t + rr * 256;
            int r = idx >> 4, g = (idx & 15) << 2;
            *(float4*)&ks[r][g] = *(const float4*)(kp + (size_t)(krow0 + r) * DIM + kc + g);
        }
        __syncthreads();
#pragma unroll
        for (int k4 = 0; k4 < 16; ++k4) {
            float4 qv = *(const float4*)&qs[tq][k4 << 2];
            float4 k0 = *(const float4*)&ks[ts][k4 << 2];
            float4 k1 = *(const float4*)&ks[ts + 16][k4 << 2];
            float4 wv = *(const float4*)&ws2[kc + (k4 << 2)];
            acc0 = fmaf(wv.x, tanh_fast(qv.x + k0.x), acc0);
            acc0 = fmaf(wv.y, tanh_fast(qv.y + k0.y), acc0);
            acc0 = fmaf(wv.z, tanh_fast(qv.z + k0.z), acc0);
            acc0 = fmaf(wv.w, tanh_fast(qv.w + k0.w), acc0);
            acc1 = fmaf(wv.x, tanh_fast(qv.x + k1.x), acc1);
            acc1 = fmaf(wv.y, tanh_fast(qv.y + k1.y), acc1);
            acc1 = fmaf(wv.z, tanh_fast(qv.z + k1.z), acc1);
            acc1 = fmaf(wv.w, tanh_fast(qv.w + k1.w), acc1);
        }
        __syncthreads();
    }
    scores[(size_t)(qrow0 + tq) * SLEN + sb + ts]      = acc0;
    scores[(size_t)(qrow0 + tq) * SLEN + sb + ts + 16] = acc1;
}

// Row softmax over 1024 scores. One block per (b,q) row.
__global__ __launch_bounds__(256) void softmax_kernel(
    const float* __restrict__ scores, float* __restrict__ attn)
{
    const int row = blockIdx.x;
    const int t   = threadIdx.x;
    __shared__ float redm[4];
    __shared__ float reds[4];
    float4 v = *(const float4*)(scores + (size_t)row * SLEN + (t << 2));
    float mx = fmaxf(fmaxf(v.x, v.y), fmaxf(v.z, v.w));
#pragma unroll
    for (int off = 32; off; off >>= 1) mx = fmaxf(mx, __shfl_xor(mx, off, 64));
    if ((t & 63) == 0) redm[t >> 6] = mx;
    __syncthreads();
    mx = fmaxf(fmaxf(redm[0], redm[1]), fmaxf(redm[2], redm[3]));
    const float L2E = 1.4426950408889634f;
    float4 e;
    e.x = fast_exp2((v.x - mx) * L2E);
    e.y = fast_exp2((v.y - mx) * L2E);
    e.z = fast_exp2((v.z - mx) * L2E);
    e.w = fast_exp2((v.w - mx) * L2E);
    float s = e.x + e.y + e.z + e.w;
#pragma unroll
    for (int off = 32; off; off >>= 1) s += __shfl_xor(s, off, 64);
    if ((t & 63) == 0) reds[t >> 6] = s;
    __syncthreads();
    s = reds[0] + reds[1] + reds[2] + reds[3];
    float r = fast_rcp(s);
    e.x *= r; e.y *= r; e.z *= r; e.w *= r;
    *(float4*)(attn + (size_t)row * SLEN + (t << 2)) = e;
}

// out[b*64+q][v] += attn[b*64+q][s] * values[b*1024+s][v], K(=s) split across
// blockIdx.y (8 chunks of 128) with f32 atomics; out zeroed by hipMemsetAsync.
// Grid: (vt=8, kt=8, b=4); tile 64q x 64v.
__global__ __launch_bounds__(256) void av_gemm(
    const float* __restrict__ attn, const float* __restrict__ values,
    float* __restrict__ out)
{
    __shared__ __align__(16) float As[32][68];
    __shared__ __align__(16) float Bs[32][68];
    const int t  = threadIdx.x;
    const int nb = blockIdx.x * 64;
    const int kb = blockIdx.y * 128;
    const int b  = blockIdx.z;
    const int tx = t & 15, ty = t >> 4;
    float acc[4][4] = {};
    for (int kc = 0; kc < 128; kc += 32) {
        const int k0 = kb + kc;
#pragma unroll
        for (int r = 0; r < 2; ++r) {
            int idx = t + r * 256;
            int m   = idx >> 3;
            int k4  = (idx & 7) << 2;
            float4 av = *(const float4*)(attn + (size_t)(b * 64 + m) * SLEN + k0 + k4);
            As[k4 + 0][m] = av.x; As[k4 + 1][m] = av.y;
            As[k4 + 2][m] = av.z; As[k4 + 3][m] = av.w;
            int kk = idx >> 4;
            int g  = (idx & 15) << 2;
            *(float4*)&Bs[kk][g] =
                *(const float4*)(values + (size_t)(b * 1024 + k0 + kk) * DIM + nb + g);
        }
        __syncthreads();
#pragma unroll
        for (int k = 0; k < 32; ++k) {
            float4 a  = *(const float4*)&As[k][ty << 2];
            float4 bv = *(const float4*)&Bs[k][tx << 2];
            float am[4] = {a.x, a.y, a.z, a.w};
            float bn[4] = {bv.x, bv.y, bv.z, bv.w};
#pragma unroll
            for (int i = 0; i < 4; ++i)
#pragma unroll
                for (int j = 0; j < 4; ++j)
                    acc[i][j] = fmaf(am[i], bn[j], acc[i][j]);
        }
        __syncthreads();
    }
#pragma unroll
    for (int i = 0; i < 4; ++i) {
        int row = b * 64 + (ty << 2) + i;
#pragma unroll
        for (int j = 0; j < 4; ++j)
            atomicAdd(&out[(size_t)row * DIM + nb + (tx << 2) + j], acc[i][j]);
    }
}

extern "C" void kernel_launch(void* const* d_in, const int* in_sizes, int n_in,
                              void* d_out, int out_size, void* d_ws, size_t ws_size,
                              hipStream_t stream) {
    const float* queries = (const float*)d_in[0];
    const float* keys    = (const float*)d_in[1];
    const float* values  = (const float*)d_in[2];
    const float* W1      = (const float*)d_in[3];
    const float* b1      = (const float*)d_in[4];
    const float* w2      = (const float*)d_in[5];
    float* out = (float*)d_out;

    float* qp = (float*)d_ws;               // 256*512 f32   (0.5 MB)
    float* kp = qp + 256 * 512;             // 4096*512 f32  (8 MB)
    float* sc = kp + 4096 * 512;            // 256*1024 f32  (1 MB)
    float* at = sc + 256 * 1024;            // 256*1024 f32  (1 MB)
    (void)in_sizes; (void)n_in; (void)ws_size;

    proj_gemm<<<dim3(4, 8), 256, 0, stream>>>(queries, W1, nullptr, qp, 0);
    proj_gemm<<<dim3(64, 8), 256, 0, stream>>>(keys, W1, b1, kp, 512);
    scores_kernel<<<dim3(32, 4, 4), 256, 0, stream>>>(qp, kp, w2, sc);
    softmax_kernel<<<dim3(256), 256, 0, stream>>>(sc, at);
    hipMemsetAsync(d_out, 0, (size_t)out_size * sizeof(float), stream);
    av_gemm<<<dim3(8, 8, 4), 256, 0, stream>>>(at, values, out);
}

// Round 2
// 162.493 us; speedup vs baseline: 1.2460x; 1.2460x over previous
//
#include <hip/hip_runtime.h>

// AdditiveAttention: b=4, n_q=64, s=1024, Q_DIM=K_DIM=HID=VDIM=512, f32 in/out.
// R2: projections via bf16 MFMA (fused q+k GEMM, cast fused into staging);
//     scores tile 16x16 (1024 blocks) for occupancy.

static constexpr int SLEN = 1024;
static constexpr int DIM  = 512;

typedef __attribute__((ext_vector_type(8))) short bf16x8;
typedef __attribute__((ext_vector_type(4))) float f32x4;

__device__ __forceinline__ float fast_exp2(float x) {
    return __builtin_amdgcn_exp2f(x);
}
__device__ __forceinline__ float fast_rcp(float x) {
    return __builtin_amdgcn_rcpf(x);
}
// tanh(x) = 1 - 2/(1+e^{2x}); saturates correctly at +-inf.
__device__ __forceinline__ float tanh_fast(float x) {
    float e = fast_exp2(x * 2.885390081777927f);
    return 1.0f - 2.0f * fast_rcp(1.0f + e);
}
__device__ __forceinline__ unsigned int f2bf(float f) {
    unsigned int u = __float_as_uint(f);
    u += 0x7FFF + ((u >> 16) & 1);   // RNE
    return u >> 16;
}

// Fused q_proj / k_proj GEMM, bf16 MFMA, f32 in/out.
// C[m][n] = sum_k A[m][k] * W1[n][col_off+k]  (+ bias[n])
// blocks 0..511: k_proj (A=keys M=4096, col_off=512, bias=b1, C=kp)
// blocks 512..543: q_proj (A=queries M=256, col_off=0, C=qp)
// Block: 256 thr = 4 waves (2x2), tile 64x64, BK=32, each wave 32x32 (2x2 MFMA).
__global__ __launch_bounds__(256) void proj_mfma(
    const float* __restrict__ queries, const float* __restrict__ keys,
    const float* __restrict__ W1, const float* __restrict__ b1,
    float* __restrict__ qp, float* __restrict__ kp)
{
    __shared__ __align__(16) unsigned short As[64][32];
    __shared__ __align__(16) unsigned short Ws[64][32];

    const int bx = blockIdx.x;
    const float* A;
    float* C;
    const float* bias;
    int mb, nb, col_off;
    if (bx < 512) {
        A = keys; C = kp; bias = b1; col_off = 512;
        mb = (bx >> 3) * 64; nb = (bx & 7) * 64;
    } else {
        int b2 = bx - 512;
        A = queries; C = qp; bias = nullptr; col_off = 0;
        mb = (b2 >> 3) * 64; nb = (b2 & 7) * 64;
    }

    const int t = threadIdx.x;
    const int srow = t >> 2;          // 0..63
    const int skg  = (t & 3) * 8;     // k-offset 0,8,16,24
    const int l      = t & 63;
    const int wv     = t >> 6;        // wave 0..3
    const int wm     = (wv & 1) * 32;
    const int wn     = (wv >> 1) * 32;
    const int lane16 = l & 15;
    const int quad   = l >> 4;

    f32x4 acc[2][2] = {{{0.f,0.f,0.f,0.f},{0.f,0.f,0.f,0.f}},
                       {{0.f,0.f,0.f,0.f},{0.f,0.f,0.f,0.f}}};

    for (int kc = 0; kc < DIM; kc += 32) {
        // stage A tile (64 x 32) with f32->bf16 convert
        {
            const float* src = A + (size_t)(mb + srow) * DIM + kc + skg;
            float4 v0 = ((const float4*)src)[0];
            float4 v1 = ((const float4*)src)[1];
            uint4 p;
            p.x = f2bf(v0.x) | (f2bf(v0.y) << 16);
            p.y = f2bf(v0.z) | (f2bf(v0.w) << 16);
            p.z = f2bf(v1.x) | (f2bf(v1.y) << 16);
            p.w = f2bf(v1.z) | (f2bf(v1.w) << 16);
            *(uint4*)&As[srow][skg] = p;
        }
        // stage W tile (64 rows of W1 = output cols, 32 k) with convert
        {
            const float* src = W1 + (size_t)(nb + srow) * 1024 + col_off + kc + skg;
            float4 v0 = ((const float4*)src)[0];
            float4 v1 = ((const float4*)src)[1];
            uint4 p;
            p.x = f2bf(v0.x) | (f2bf(v0.y) << 16);
            p.y = f2bf(v0.z) | (f2bf(v0.w) << 16);
            p.z = f2bf(v1.x) | (f2bf(v1.y) << 16);
            p.w = f2bf(v1.z) | (f2bf(v1.w) << 16);
            *(uint4*)&Ws[srow][skg] = p;
        }
        __syncthreads();

        bf16x8 a0 = *(const bf16x8*)&As[wm + lane16][quad * 8];
        bf16x8 a1 = *(const bf16x8*)&As[wm + 16 + lane16][quad * 8];
        bf16x8 b0 = *(const bf16x8*)&Ws[wn + lane16][quad * 8];
        bf16x8 b1f = *(const bf16x8*)&Ws[wn + 16 + lane16][quad * 8];

        acc[0][0] = __builtin_amdgcn_mfma_f32_16x16x32_bf16(a0, b0, acc[0][0], 0, 0, 0);
        acc[0][1] = __builtin_amdgcn_mfma_f32_16x16x32_bf16(a0, b1f, acc[0][1], 0, 0, 0);
        acc[1][0] = __builtin_amdgcn_mfma_f32_16x16x32_bf16(a1, b0, acc[1][0], 0, 0, 0);
        acc[1][1] = __builtin_amdgcn_mfma_f32_16x16x32_bf16(a1, b1f, acc[1][1], 0, 0, 0);
        __syncthreads();
    }

#pragma unroll
    for (int mi = 0; mi < 2; ++mi) {
#pragma unroll
        for (int ni = 0; ni < 2; ++ni) {
            int col = nb + wn + 16 * ni + lane16;
            float bv = bias ? bias[col] : 0.0f;
#pragma unroll
            for (int r = 0; r < 4; ++r) {
                int row = mb + wm + 16 * mi + quad * 4 + r;
                C[(size_t)row * DIM + col] = acc[mi][ni][r] + bv;
            }
        }
    }
}

// scores[b,q,s] = sum_h w2[h] * tanh(qp[b*64+q][h] + kp[b*1024+s][h])
// Tile 16q x 16s, one output per thread. Grid (64, 4, 4) = 1024 blocks.
__global__ __launch_bounds__(256) void scores_kernel(
    const float* __restrict__ qp, const float* __restrict__ kp,
    const float* __restrict__ w2, float* __restrict__ scores)
{
    __shared__ __align__(16) float qs[16][68];
    __shared__ __align__(16) float ks[16][68];
    __shared__ __align__(16) float ws2[512];
    const int t     = threadIdx.x;
    const int sb    = blockIdx.x * 16;
    const int qrow0 = blockIdx.z * 64 + blockIdx.y * 16;
    const int krow0 = blockIdx.z * 1024 + sb;

    if (t < 128) *(float4*)&ws2[t << 2] = *(const float4*)(w2 + (t << 2));

    const int tq = t >> 4;
    const int ts = t & 15;
    float acc = 0.f;

    for (int kc = 0; kc < DIM; kc += 64) {
        {
            int r = t >> 4, g = (t & 15) << 2;
            *(float4*)&qs[r][g] = *(const float4*)(qp + (size_t)(qrow0 + r) * DIM + kc + g);
            *(float4*)&ks[r][g] = *(const float4*)(kp + (size_t)(krow0 + r) * DIM + kc + g);
        }
        __syncthreads();
#pragma unroll
        for (int k4 = 0; k4 < 16; ++k4) {
            float4 qv = *(const float4*)&qs[tq][k4 << 2];
            float4 kv = *(const float4*)&ks[ts][k4 << 2];
            float4 wv = *(const float4*)&ws2[kc + (k4 << 2)];
            acc = fmaf(wv.x, tanh_fast(qv.x + kv.x), acc);
            acc = fmaf(wv.y, tanh_fast(qv.y + kv.y), acc);
            acc = fmaf(wv.z, tanh_fast(qv.z + kv.z), acc);
            acc = fmaf(wv.w, tanh_fast(qv.w + kv.w), acc);
        }
        __syncthreads();
    }
    scores[(size_t)(qrow0 + tq) * SLEN + sb + ts] = acc;
}

// Row softmax over 1024 scores. One block per (b,q) row.
__global__ __launch_bounds__(256) void softmax_kernel(
    const float* __restrict__ scores, float* __restrict__ attn)
{
    const int row = blockIdx.x;
    const int t   = threadIdx.x;
    __shared__ float redm[4];
    __shared__ float reds[4];
    float4 v = *(const float4*)(scores + (size_t)row * SLEN + (t << 2));
    float mx = fmaxf(fmaxf(v.x, v.y), fmaxf(v.z, v.w));
#pragma unroll
    for (int off = 32; off; off >>= 1) mx = fmaxf(mx, __shfl_xor(mx, off, 64));
    if ((t & 63) == 0) redm[t >> 6] = mx;
    __syncthreads();
    mx = fmaxf(fmaxf(redm[0], redm[1]), fmaxf(redm[2], redm[3]));
    const float L2E = 1.4426950408889634f;
    float4 e;
    e.x = fast_exp2((v.x - mx) * L2E);
    e.y = fast_exp2((v.y - mx) * L2E);
    e.z = fast_exp2((v.z - mx) * L2E);
    e.w = fast_exp2((v.w - mx) * L2E);
    float s = e.x + e.y + e.z + e.w;
#pragma unroll
    for (int off = 32; off; off >>= 1) s += __shfl_xor(s, off, 64);
    if ((t & 63) == 0) reds[t >> 6] = s;
    __syncthreads();
    s = reds[0] + reds[1] + reds[2] + reds[3];
    float r = fast_rcp(s);
    e.x *= r; e.y *= r; e.z *= r; e.w *= r;
    *(float4*)(attn + (size_t)row * SLEN + (t << 2)) = e;
}

// out[b*64+q][v] += attn[b*64+q][s] * values[b*1024+s][v]; split-K over
// blockIdx.y (8 chunks of 128) with f32 atomics; out zeroed via hipMemsetAsync.
__global__ __launch_bounds__(256) void av_gemm(
    const float* __restrict__ attn, const float* __restrict__ values,
    float* __restrict__ out)
{
    __shared__ __align__(16) float As[32][68];
    __shared__ __align__(16) float Bs[32][68];
    const int t  = threadIdx.x;
    const int nb = blockIdx.x * 64;
    const int kb = blockIdx.y * 128;
    const int b  = blockIdx.z;
    const int tx = t & 15, ty = t >> 4;
    float acc[4][4] = {};
    for (int kc = 0; kc < 128; kc += 32) {
        const int k0 = kb + kc;
#pragma unroll
        for (int r = 0; r < 2; ++r) {
            int idx = t + r * 256;
            int m   = idx >> 3;
            int k4  = (idx & 7) << 2;
            float4 av = *(const float4*)(attn + (size_t)(b * 64 + m) * SLEN + k0 + k4);
            As[k4 + 0][m] = av.x; As[k4 + 1][m] = av.y;
            As[k4 + 2][m] = av.z; As[k4 + 3][m] = av.w;
            int kk = idx >> 4;
            int g  = (idx & 15) << 2;
            *(float4*)&Bs[kk][g] =
                *(const float4*)(values + (size_t)(b * 1024 + k0 + kk) * DIM + nb + g);
        }
        __syncthreads();
#pragma unroll
        for (int k = 0; k < 32; ++k) {
            float4 a  = *(const float4*)&As[k][ty << 2];
            float4 bv = *(const float4*)&Bs[k][tx << 2];
            float am[4] = {a.x, a.y, a.z, a.w};
            float bn[4] = {bv.x, bv.y, bv.z, bv.w};
#pragma unroll
            for (int i = 0; i < 4; ++i)
#pragma unroll
                for (int j = 0; j < 4; ++j)
                    acc[i][j] = fmaf(am[i], bn[j], acc[i][j]);
        }
        __syncthreads();
    }
#pragma unroll
    for (int i = 0; i < 4; ++i) {
        int row = b * 64 + (ty << 2) + i;
#pragma unroll
        for (int j = 0; j < 4; ++j)
            atomicAdd(&out[(size_t)row * DIM + nb + (tx << 2) + j], acc[i][j]);
    }
}

extern "C" void kernel_launch(void* const* d_in, const int* in_sizes, int n_in,
                              void* d_out, int out_size, void* d_ws, size_t ws_size,
                              hipStream_t stream) {
    const float* queries = (const float*)d_in[0];
    const float* keys    = (const float*)d_in[1];
    const float* values  = (const float*)d_in[2];
    const float* W1      = (const float*)d_in[3];
    const float* b1      = (const float*)d_in[4];
    const float* w2      = (const float*)d_in[5];
    float* out = (float*)d_out;

    float* qp = (float*)d_ws;               // 256*512 f32
    float* kp = qp + 256 * 512;             // 4096*512 f32
    float* sc = kp + 4096 * 512;            // 256*1024 f32
    float* at = sc + 256 * 1024;            // 256*1024 f32
    (void)in_sizes; (void)n_in; (void)ws_size;

    proj_mfma<<<dim3(544), 256, 0, stream>>>(queries, keys, W1, b1, qp, kp);
    scores_kernel<<<dim3(64, 4, 4), 256, 0, stream>>>(qp, kp, w2, sc);
    softmax_kernel<<<dim3(256), 256, 0, stream>>>(sc, at);
    hipMemsetAsync(d_out, 0, (size_t)out_size * sizeof(float), stream);
    av_gemm<<<dim3(8, 8, 4), 256, 0, stream>>>(at, values, out);
}

// Round 3
// 161.221 us; speedup vs baseline: 1.2558x; 1.0079x over previous
//
#include <hip/hip_runtime.h>

// AdditiveAttention: b=4, n_q=64, s=1024, Q_DIM=K_DIM=HID=VDIM=512, f32 in/out.
// R3: bf16 pre-convert + global_load_lds MFMA proj (XOR-swizzled LDS);
//     scores split-h (2048 blocks), Σw·r identity (const folds out of softmax);
//     min-based softmax; av_gemm split-K 16.

static constexpr int SLEN = 1024;
static constexpr int DIM  = 512;
static constexpr float TANH_SCALE = 2.885390081777927f;  // 2*log2(e)

typedef __attribute__((ext_vector_type(8))) short bf16x8;
typedef __attribute__((ext_vector_type(4))) float f32x4;

__device__ __forceinline__ float fast_exp2(float x) { return __builtin_amdgcn_exp2f(x); }
__device__ __forceinline__ float fast_rcp(float x)  { return __builtin_amdgcn_rcpf(x); }

__device__ __forceinline__ unsigned int f2bf(float f) {
    unsigned int u = __float_as_uint(f);
    u += 0x7FFF + ((u >> 16) & 1);   // RNE
    return u >> 16;
}

__device__ __forceinline__ void async_copy16(const void* g, void* l) {
    __builtin_amdgcn_global_load_lds(
        (const __attribute__((address_space(1))) unsigned int*)g,
        (__attribute__((address_space(3))) unsigned int*)l, 16, 0, 0);
}

// f32 -> bf16 pre-convert: queries (131072), keys (2097152), W1 (524288).
// One float4 -> ushort4 per thread. 688128 float4s total, grid 2688.
__global__ __launch_bounds__(256) void convert_bf16(
    const float* __restrict__ q, const float* __restrict__ k,
    const float* __restrict__ w, unsigned short* __restrict__ qb,
    unsigned short* __restrict__ kb, unsigned short* __restrict__ wb)
{
    int id = blockIdx.x * 256 + threadIdx.x;
    const float* src; unsigned short* dst; int off;
    if (id < 32768)        { src = q; dst = qb; off = id; }
    else if (id < 557056)  { src = k; dst = kb; off = id - 32768; }
    else                   { src = w; dst = wb; off = id - 557056; }
    float4 v = ((const float4*)src)[off];
    ushort4 o;
    o.x = (unsigned short)f2bf(v.x); o.y = (unsigned short)f2bf(v.y);
    o.z = (unsigned short)f2bf(v.z); o.w = (unsigned short)f2bf(v.w);
    ((ushort4*)dst)[off] = o;
}

// Fused q_proj/k_proj GEMM, bf16 MFMA, global_load_lds staging.
// C[m][n] = (sum_k A[m][k]*W1[n][col_off+k] + bias[n]) * TANH_SCALE
// blocks 0..511: k_proj (A=kb, M=4096, col_off=512, bias=b1, C=kp)
// blocks 512..543: q_proj (A=qb, M=256, col_off=0, C=qp)
// 256 thr = 4 waves (2x2), tile 64x64, BK=64, wave does 32x32 (2x2 MFMA x2 k).
// LDS rows are 128 B (64 bf16), DMA-packed; k-chunks XOR-swizzled by row&7 so
// frag ds_read_b128 is <=2-way (free). Pad would break global_load_lds.
__global__ __launch_bounds__(256) void proj_mfma(
    const unsigned short* __restrict__ qb, const unsigned short* __restrict__ kb,
    const unsigned short* __restrict__ wb, const float* __restrict__ b1,
    float* __restrict__ qp, float* __restrict__ kp)
{
    __shared__ __align__(16) unsigned short As[64][64];
    __shared__ __align__(16) unsigned short Ws[64][64];

    const int bx = blockIdx.x;
    const unsigned short* A; float* C; const float* bias; int mb, nb, col_off;
    if (bx < 512) {
        A = kb; C = kp; bias = b1; col_off = 512;
        mb = (bx >> 3) * 64; nb = (bx & 7) * 64;
    } else {
        int b2 = bx - 512;
        A = qb; C = qp; bias = nullptr; col_off = 0;
        mb = (b2 >> 3) * 64; nb = (b2 & 7) * 64;
    }

    const int t = threadIdx.x;
    const int l = t & 63;
    const int wv = t >> 6;                  // wave 0..3
    const int wm = (wv & 1) * 32;
    const int wn = (wv >> 1) * 32;
    const int lane16 = l & 15;
    const int quad   = l >> 4;
    // staging: each instr covers 8 rows x 128 B; lane: row=l>>3, chunk=(l&7)^row
    const int r8   = l >> 3;
    const int schk = (l & 7) ^ r8;          // swizzled 16B k-chunk index

    f32x4 acc[2][2] = {{{0.f,0.f,0.f,0.f},{0.f,0.f,0.f,0.f}},
                       {{0.f,0.f,0.f,0.f},{0.f,0.f,0.f,0.f}}};

    for (int kc = 0; kc < DIM; kc += 64) {
#pragma unroll
        for (int i = 0; i < 2; ++i) {
            int rbase = wv * 16 + i * 8;
            int rowA = mb + rbase + r8;
            async_copy16(A + (size_t)rowA * DIM + kc + schk * 8, &As[rbase][0]);
            int rowW = nb + rbase + r8;
            async_copy16(wb + (size_t)rowW * 1024 + col_off + kc + schk * 8, &Ws[rbase][0]);
        }
        __syncthreads();  // compiler drains vmcnt before s_barrier

#pragma unroll
        for (int ks = 0; ks < 2; ++ks) {
            int cc = ks * 4 + quad;
            int sw = (cc ^ (lane16 & 7)) << 3;
            bf16x8 a0 = *(const bf16x8*)&As[wm + lane16][sw];
            bf16x8 a1 = *(const bf16x8*)&As[wm + 16 + lane16][sw];
            bf16x8 b0 = *(const bf16x8*)&Ws[wn + lane16][sw];
            bf16x8 b1v = *(const bf16x8*)&Ws[wn + 16 + lane16][sw];
            acc[0][0] = __builtin_amdgcn_mfma_f32_16x16x32_bf16(a0, b0,  acc[0][0], 0, 0, 0);
            acc[0][1] = __builtin_amdgcn_mfma_f32_16x16x32_bf16(a0, b1v, acc[0][1], 0, 0, 0);
            acc[1][0] = __builtin_amdgcn_mfma_f32_16x16x32_bf16(a1, b0,  acc[1][0], 0, 0, 0);
            acc[1][1] = __builtin_amdgcn_mfma_f32_16x16x32_bf16(a1, b1v, acc[1][1], 0, 0, 0);
        }
        __syncthreads();
    }

#pragma unroll
    for (int mi = 0; mi < 2; ++mi) {
#pragma unroll
        for (int ni = 0; ni < 2; ++ni) {
            int col = nb + wn + 16 * ni + lane16;
            float bv = bias ? bias[col] : 0.0f;
#pragma unroll
            for (int r = 0; r < 4; ++r) {
                int row = mb + wm + 16 * mi + quad * 4 + r;
                C[(size_t)row * DIM + col] = (acc[mi][ni][r] + bv) * TANH_SCALE;
            }
        }
    }
}

// t[b,q,s] = sum_h w2[h] * rcp(1 + exp2(qp'[q][h] + kp'[s][h]))   (partial, h-half)
// where qp',kp' are pre-scaled by 2*log2(e). True logits = C - 2t; the constant
// C = sum(w2) cancels in softmax, so only t is accumulated (atomicAdd, 2 halves).
// Tile 16q x 16s. Grid (64 st, 8 = 4 qt x 2 half, 4 b) = 2048 blocks.
__global__ __launch_bounds__(256) void scores_kernel(
    const float* __restrict__ qp, const float* __restrict__ kp,
    const float* __restrict__ w2, float* __restrict__ sc)
{
    __shared__ __align__(16) float qs[16][68];
    __shared__ __align__(16) float ks[16][68];
    __shared__ __align__(16) float ws2[256];
    const int t     = threadIdx.x;
    const int sb    = blockIdx.x * 16;
    const int qt    = blockIdx.y & 3;
    const int half  = blockIdx.y >> 2;
    const int kbase = half * 256;
    const int qrow0 = blockIdx.z * 64 + qt * 16;
    const int krow0 = blockIdx.z * 1024 + sb;

    if (t < 64) *(float4*)&ws2[t << 2] = *(const float4*)(w2 + kbase + (t << 2));

    const int tq = t >> 4;
    const int ts = t & 15;
    float acc = 0.f;

    for (int kc = 0; kc < 256; kc += 64) {
        {
            int r = t >> 4, g = (t & 15) << 2;
            *(float4*)&qs[r][g] = *(const float4*)(qp + (size_t)(qrow0 + r) * DIM + kbase + kc + g);
            *(float4*)&ks[r][g] = *(const float4*)(kp + (size_t)(krow0 + r) * DIM + kbase + kc + g);
        }
        __syncthreads();
#pragma unroll
        for (int k4 = 0; k4 < 16; ++k4) {
            float4 qv = *(const float4*)&qs[tq][k4 << 2];
            float4 kv = *(const float4*)&ks[ts][k4 << 2];
            float4 wv = *(const float4*)&ws2[kc + (k4 << 2)];
            acc = fmaf(wv.x, fast_rcp(1.0f + fast_exp2(qv.x + kv.x)), acc);
            acc = fmaf(wv.y, fast_rcp(1.0f + fast_exp2(qv.y + kv.y)), acc);
            acc = fmaf(wv.z, fast_rcp(1.0f + fast_exp2(qv.z + kv.z)), acc);
            acc = fmaf(wv.w, fast_rcp(1.0f + fast_exp2(qv.w + kv.w)), acc);
        }
        __syncthreads();
    }
    atomicAdd(&sc[(size_t)(qrow0 + tq) * SLEN + sb + ts], acc);
}

// Softmax over s of logits (C - 2t): max logit <-> min t;
// e = exp2((mn - t) * 2*log2(e)). One block per (b,q) row.
__global__ __launch_bounds__(256) void softmax_kernel(
    const float* __restrict__ sc, float* __restrict__ attn)
{
    const int row = blockIdx.x;
    const int t   = threadIdx.x;
    __shared__ float redm[4];
    __shared__ float reds[4];
    float4 v = *(const float4*)(sc + (size_t)row * SLEN + (t << 2));
    float mn = fminf(fminf(v.x, v.y), fminf(v.z, v.w));
#pragma unroll
    for (int off = 32; off; off >>= 1) mn = fminf(mn, __shfl_xor(mn, off, 64));
    if ((t & 63) == 0) redm[t >> 6] = mn;
    __syncthreads();
    mn = fminf(fminf(redm[0], redm[1]), fminf(redm[2], redm[3]));
    float4 e;
    e.x = fast_exp2((mn - v.x) * TANH_SCALE);
    e.y = fast_exp2((mn - v.y) * TANH_SCALE);
    e.z = fast_exp2((mn - v.z) * TANH_SCALE);
    e.w = fast_exp2((mn - v.w) * TANH_SCALE);
    float s = e.x + e.y + e.z + e.w;
#pragma unroll
    for (int off = 32; off; off >>= 1) s += __shfl_xor(s, off, 64);
    if ((t & 63) == 0) reds[t >> 6] = s;
    __syncthreads();
    s = reds[0] + reds[1] + reds[2] + reds[3];
    float r = fast_rcp(s);
    e.x *= r; e.y *= r; e.z *= r; e.w *= r;
    *(float4*)(attn + (size_t)row * SLEN + (t << 2)) = e;
}

// out[b*64+q][v] += attn[b*64+q][s] * values[b*1024+s][v]; split-K over
// blockIdx.y (16 chunks of 64) with f32 atomics; out zeroed via hipMemsetAsync.
__global__ __launch_bounds__(256) void av_gemm(
    const float* __restrict__ attn, const float* __restrict__ values,
    float* __restrict__ out)
{
    __shared__ __align__(16) float As[32][68];
    __shared__ __align__(16) float Bs[32][68];
    const int t  = threadIdx.x;
    const int nb = blockIdx.x * 64;
    const int kb = blockIdx.y * 64;
    const int b  = blockIdx.z;
    const int tx = t & 15, ty = t >> 4;
    float acc[4][4] = {};
    for (int kc = 0; kc < 64; kc += 32) {
        const int k0 = kb + kc;
#pragma unroll
        for (int r = 0; r < 2; ++r) {
            int idx = t + r * 256;
            int m   = idx >> 3;
            int k4  = (idx & 7) << 2;
            float4 av = *(const float4*)(attn + (size_t)(b * 64 + m) * SLEN + k0 + k4);
            As[k4 + 0][m] = av.x; As[k4 + 1][m] = av.y;
            As[k4 + 2][m] = av.z; As[k4 + 3][m] = av.w;
            int kk = idx >> 4;
            int g  = (idx & 15) << 2;
            *(float4*)&Bs[kk][g] =
                *(const float4*)(values + (size_t)(b * 1024 + k0 + kk) * DIM + nb + g);
        }
        __syncthreads();
#pragma unroll
        for (int k = 0; k < 32; ++k) {
            float4 a  = *(const float4*)&As[k][ty << 2];
            float4 bv = *(const float4*)&Bs[k][tx << 2];
            float am[4] = {a.x, a.y, a.z, a.w};
            float bn[4] = {bv.x, bv.y, bv.z, bv.w};
#pragma unroll
            for (int i = 0; i < 4; ++i)
#pragma unroll
                for (int j = 0; j < 4; ++j)
                    acc[i][j] = fmaf(am[i], bn[j], acc[i][j]);
        }
        __syncthreads();
    }
#pragma unroll
    for (int i = 0; i < 4; ++i) {
        int row = b * 64 + (ty << 2) + i;
#pragma unroll
        for (int j = 0; j < 4; ++j)
            atomicAdd(&out[(size_t)row * DIM + nb + (tx << 2) + j], acc[i][j]);
    }
}

extern "C" void kernel_launch(void* const* d_in, const int* in_sizes, int n_in,
                              void* d_out, int out_size, void* d_ws, size_t ws_size,
                              hipStream_t stream) {
    const float* queries = (const float*)d_in[0];
    const float* keys    = (const float*)d_in[1];
    const float* values  = (const float*)d_in[2];
    const float* W1      = (const float*)d_in[3];
    const float* b1      = (const float*)d_in[4];
    const float* w2      = (const float*)d_in[5];
    float* out = (float*)d_out;

    float* qp = (float*)d_ws;                       // 256*512 f32
    float* kp = qp + 256 * 512;                     // 4096*512 f32
    float* sc = kp + 4096 * 512;                    // 256*1024 f32
    float* at = sc + 256 * 1024;                    // 256*1024 f32
    unsigned short* qbf = (unsigned short*)(at + 256 * 1024);  // 256*512 bf16
    unsigned short* kbf = qbf + 256 * 512;                     // 4096*512 bf16
    unsigned short* wbf = kbf + 4096 * 512;                    // 512*1024 bf16
    (void)in_sizes; (void)n_in; (void)ws_size;

    hipMemsetAsync(sc, 0, 256 * 1024 * sizeof(float), stream);
    hipMemsetAsync(d_out, 0, (size_t)out_size * sizeof(float), stream);
    convert_bf16<<<dim3(2688), 256, 0, stream>>>(queries, keys, W1, qbf, kbf, wbf);
    proj_mfma<<<dim3(544), 256, 0, stream>>>(qbf, kbf, wbf, b1, qp, kp);
    scores_kernel<<<dim3(64, 8, 4), 256, 0, stream>>>(qp, kp, w2, sc);
    softmax_kernel<<<dim3(256), 256, 0, stream>>>(sc, at);
    av_gemm<<<dim3(8, 16, 4), 256, 0, stream>>>(at, values, out);
}

// Round 4
// 127.006 us; speedup vs baseline: 1.5942x; 1.2694x over previous
//
#include <hip/hip_runtime.h>

// AdditiveAttention: b=4, n_q=64, s=1024, Q_DIM=K_DIM=HID=VDIM=512, f32 in/out.
// R4: no atomics anywhere — av_gemm writes split-K partials + reduce kernel;
//     scores writes per-half buffers (softmax sums); scores 16x32 tile (2 acc).

static constexpr int SLEN = 1024;
static constexpr int DIM  = 512;
static constexpr float TANH_SCALE = 2.885390081777927f;  // 2*log2(e)

typedef __attribute__((ext_vector_type(8))) short bf16x8;
typedef __attribute__((ext_vector_type(4))) float f32x4;

__device__ __forceinline__ float fast_exp2(float x) { return __builtin_amdgcn_exp2f(x); }
__device__ __forceinline__ float fast_rcp(float x)  { return __builtin_amdgcn_rcpf(x); }

__device__ __forceinline__ unsigned int f2bf(float f) {
    unsigned int u = __float_as_uint(f);
    u += 0x7FFF + ((u >> 16) & 1);   // RNE
    return u >> 16;
}

__device__ __forceinline__ void async_copy16(const void* g, void* l) {
    __builtin_amdgcn_global_load_lds(
        (const __attribute__((address_space(1))) unsigned int*)g,
        (__attribute__((address_space(3))) unsigned int*)l, 16, 0, 0);
}

// f32 -> bf16 pre-convert: queries (131072), keys (2097152), W1 (524288) elems.
__global__ __launch_bounds__(256) void convert_bf16(
    const float* __restrict__ q, const float* __restrict__ k,
    const float* __restrict__ w, unsigned short* __restrict__ qb,
    unsigned short* __restrict__ kb, unsigned short* __restrict__ wb)
{
    int id = blockIdx.x * 256 + threadIdx.x;
    const float* src; unsigned short* dst; int off;
    if (id < 32768)        { src = q; dst = qb; off = id; }
    else if (id < 557056)  { src = k; dst = kb; off = id - 32768; }
    else                   { src = w; dst = wb; off = id - 557056; }
    float4 v = ((const float4*)src)[off];
    ushort4 o;
    o.x = (unsigned short)f2bf(v.x); o.y = (unsigned short)f2bf(v.y);
    o.z = (unsigned short)f2bf(v.z); o.w = (unsigned short)f2bf(v.w);
    ((ushort4*)dst)[off] = o;
}

// Fused q_proj/k_proj GEMM, bf16 MFMA, global_load_lds staging.
// C[m][n] = (sum_k A[m][k]*W1[n][col_off+k] + bias[n]) * TANH_SCALE
// blocks 0..511: k_proj; 512..543: q_proj. Tile 64x64, BK=64, 4 waves 2x2.
// LDS rows 128 B DMA-packed; XOR swizzle keeps ds_read_b128 <=2-way.
__global__ __launch_bounds__(256) void proj_mfma(
    const unsigned short* __restrict__ qb, const unsigned short* __restrict__ kb,
    const unsigned short* __restrict__ wb, const float* __restrict__ b1,
    float* __restrict__ qp, float* __restrict__ kp)
{
    __shared__ __align__(16) unsigned short As[64][64];
    __shared__ __align__(16) unsigned short Ws[64][64];

    const int bx = blockIdx.x;
    const unsigned short* A; float* C; const float* bias; int mb, nb, col_off;
    if (bx < 512) {
        A = kb; C = kp; bias = b1; col_off = 512;
        mb = (bx >> 3) * 64; nb = (bx & 7) * 64;
    } else {
        int b2 = bx - 512;
        A = qb; C = qp; bias = nullptr; col_off = 0;
        mb = (b2 >> 3) * 64; nb = (b2 & 7) * 64;
    }

    const int t = threadIdx.x;
    const int l = t & 63;
    const int wv = t >> 6;
    const int wm = (wv & 1) * 32;
    const int wn = (wv >> 1) * 32;
    const int lane16 = l & 15;
    const int quad   = l >> 4;
    const int r8   = l >> 3;
    const int schk = (l & 7) ^ r8;

    f32x4 acc[2][2] = {{{0.f,0.f,0.f,0.f},{0.f,0.f,0.f,0.f}},
                       {{0.f,0.f,0.f,0.f},{0.f,0.f,0.f,0.f}}};

    for (int kc = 0; kc < DIM; kc += 64) {
#pragma unroll
        for (int i = 0; i < 2; ++i) {
            int rbase = wv * 16 + i * 8;
            async_copy16(A + (size_t)(mb + rbase + r8) * DIM + kc + schk * 8, &As[rbase][0]);
            async_copy16(wb + (size_t)(nb + rbase + r8) * 1024 + col_off + kc + schk * 8, &Ws[rbase][0]);
        }
        __syncthreads();

#pragma unroll
        for (int ks = 0; ks < 2; ++ks) {
            int cc = ks * 4 + quad;
            int sw = (cc ^ (lane16 & 7)) << 3;
            bf16x8 a0  = *(const bf16x8*)&As[wm + lane16][sw];
            bf16x8 a1  = *(const bf16x8*)&As[wm + 16 + lane16][sw];
            bf16x8 b0  = *(const bf16x8*)&Ws[wn + lane16][sw];
            bf16x8 b1v = *(const bf16x8*)&Ws[wn + 16 + lane16][sw];
            acc[0][0] = __builtin_amdgcn_mfma_f32_16x16x32_bf16(a0, b0,  acc[0][0], 0, 0, 0);
            acc[0][1] = __builtin_amdgcn_mfma_f32_16x16x32_bf16(a0, b1v, acc[0][1], 0, 0, 0);
            acc[1][0] = __builtin_amdgcn_mfma_f32_16x16x32_bf16(a1, b0,  acc[1][0], 0, 0, 0);
            acc[1][1] = __builtin_amdgcn_mfma_f32_16x16x32_bf16(a1, b1v, acc[1][1], 0, 0, 0);
        }
        __syncthreads();
    }

#pragma unroll
    for (int mi = 0; mi < 2; ++mi) {
#pragma unroll
        for (int ni = 0; ni < 2; ++ni) {
            int col = nb + wn + 16 * ni + lane16;
            float bv = bias ? bias[col] : 0.0f;
#pragma unroll
            for (int r = 0; r < 4; ++r) {
                int row = mb + wm + 16 * mi + quad * 4 + r;
                C[(size_t)row * DIM + col] = (acc[mi][ni][r] + bv) * TANH_SCALE;
            }
        }
    }
}

// t[b,q,s] = sum_h w2[h] * rcp(1 + exp2(qp'+kp'))  over one h-half (256).
// True logits = C - 2t, C=sum(w2) cancels in softmax. Plain stores into
// sc[half]. Tile 16q x 32s, 2 acc chains/thread. Grid (32, 4qt x 2half, 4b).
__global__ __launch_bounds__(256) void scores_kernel(
    const float* __restrict__ qp, const float* __restrict__ kp,
    const float* __restrict__ w2, float* __restrict__ sc)
{
    __shared__ __align__(16) float qs[16][68];
    __shared__ __align__(16) float ks[32][68];
    __shared__ __align__(16) float ws2[256];
    const int t     = threadIdx.x;
    const int sb    = blockIdx.x * 32;
    const int qt    = blockIdx.y & 3;
    const int half  = blockIdx.y >> 2;
    const int kbase = half * 256;
    const int qrow0 = blockIdx.z * 64 + qt * 16;
    const int krow0 = blockIdx.z * 1024 + sb;
    float* sch = sc + (size_t)half * 256 * SLEN;

    if (t < 64) *(float4*)&ws2[t << 2] = *(const float4*)(w2 + kbase + (t << 2));

    const int tq = t >> 4;
    const int ts = t & 15;
    float acc0 = 0.f, acc1 = 0.f;

    for (int kc = 0; kc < 256; kc += 64) {
        {
            int r = t >> 4, g = (t & 15) << 2;
            *(float4*)&qs[r][g] = *(const float4*)(qp + (size_t)(qrow0 + r) * DIM + kbase + kc + g);
        }
#pragma unroll
        for (int rr = 0; rr < 2; ++rr) {
            int idx = t + rr * 256;
            int r = idx >> 4, g = (idx & 15) << 2;
            *(float4*)&ks[r][g] = *(const float4*)(kp + (size_t)(krow0 + r) * DIM + kbase + kc + g);
        }
        __syncthreads();
#pragma unroll
        for (int k4 = 0; k4 < 16; ++k4) {
            float4 qv = *(const float4*)&qs[tq][k4 << 2];
            float4 k0 = *(const float4*)&ks[ts][k4 << 2];
            float4 k1 = *(const float4*)&ks[ts + 16][k4 << 2];
            float4 wv = *(const float4*)&ws2[kc + (k4 << 2)];
            acc0 = fmaf(wv.x, fast_rcp(1.0f + fast_exp2(qv.x + k0.x)), acc0);
            acc1 = fmaf(wv.x, fast_rcp(1.0f + fast_exp2(qv.x + k1.x)), acc1);
            acc0 = fmaf(wv.y, fast_rcp(1.0f + fast_exp2(qv.y + k0.y)), acc0);
            acc1 = fmaf(wv.y, fast_rcp(1.0f + fast_exp2(qv.y + k1.y)), acc1);
            acc0 = fmaf(wv.z, fast_rcp(1.0f + fast_exp2(qv.z + k0.z)), acc0);
            acc1 = fmaf(wv.z, fast_rcp(1.0f + fast_exp2(qv.z + k1.z)), acc1);
            acc0 = fmaf(wv.w, fast_rcp(1.0f + fast_exp2(qv.w + k0.w)), acc0);
            acc1 = fmaf(wv.w, fast_rcp(1.0f + fast_exp2(qv.w + k1.w)), acc1);
        }
        __syncthreads();
    }
    sch[(size_t)(qrow0 + tq) * SLEN + sb + ts]      = acc0;
    sch[(size_t)(qrow0 + tq) * SLEN + sb + ts + 16] = acc1;
}

// Softmax: t = h0+h1; max logit <-> min t; e = exp2((mn - t)*2log2e).
__global__ __launch_bounds__(256) void softmax_kernel(
    const float* __restrict__ sc, float* __restrict__ attn)
{
    const int row = blockIdx.x;
    const int t   = threadIdx.x;
    __shared__ float redm[4];
    __shared__ float reds[4];
    float4 a = *(const float4*)(sc + (size_t)row * SLEN + (t << 2));
    float4 b = *(const float4*)(sc + (size_t)(256 + row) * SLEN + (t << 2));
    float4 v;
    v.x = a.x + b.x; v.y = a.y + b.y; v.z = a.z + b.z; v.w = a.w + b.w;
    float mn = fminf(fminf(v.x, v.y), fminf(v.z, v.w));
#pragma unroll
    for (int off = 32; off; off >>= 1) mn = fminf(mn, __shfl_xor(mn, off, 64));
    if ((t & 63) == 0) redm[t >> 6] = mn;
    __syncthreads();
    mn = fminf(fminf(redm[0], redm[1]), fminf(redm[2], redm[3]));
    float4 e;
    e.x = fast_exp2((mn - v.x) * TANH_SCALE);
    e.y = fast_exp2((mn - v.y) * TANH_SCALE);
    e.z = fast_exp2((mn - v.z) * TANH_SCALE);
    e.w = fast_exp2((mn - v.w) * TANH_SCALE);
    float s = e.x + e.y + e.z + e.w;
#pragma unroll
    for (int off = 32; off; off >>= 1) s += __shfl_xor(s, off, 64);
    if ((t & 63) == 0) reds[t >> 6] = s;
    __syncthreads();
    s = reds[0] + reds[1] + reds[2] + reds[3];
    float r = fast_rcp(s);
    e.x *= r; e.y *= r; e.z *= r; e.w *= r;
    *(float4*)(attn + (size_t)row * SLEN + (t << 2)) = e;
}

// pt[kt][b*64+q][v] = sum over 128-s chunk of attn*values. Plain stores.
// Grid (8 vt, 8 kt, 4 b); tile 64q x 64v x 128k.
__global__ __launch_bounds__(256) void av_gemm(
    const float* __restrict__ attn, const float* __restrict__ values,
    float* __restrict__ pt)
{
    __shared__ __align__(16) float As[32][68];
    __shared__ __align__(16) float Bs[32][68];
    const int t  = threadIdx.x;
    const int nb = blockIdx.x * 64;
    const int kt = blockIdx.y;
    const int kb = kt * 128;
    const int b  = blockIdx.z;
    const int tx = t & 15, ty = t >> 4;
    float acc[4][4] = {};
    for (int kc = 0; kc < 128; kc += 32) {
        const int k0 = kb + kc;
#pragma unroll
        for (int r = 0; r < 2; ++r) {
            int idx = t + r * 256;
            int m   = idx >> 3;
            int k4  = (idx & 7) << 2;
            float4 av = *(const float4*)(attn + (size_t)(b * 64 + m) * SLEN + k0 + k4);
            As[k4 + 0][m] = av.x; As[k4 + 1][m] = av.y;
            As[k4 + 2][m] = av.z; As[k4 + 3][m] = av.w;
            int kk = idx >> 4;
            int g  = (idx & 15) << 2;
            *(float4*)&Bs[kk][g] =
                *(const float4*)(values + (size_t)(b * 1024 + k0 + kk) * DIM + nb + g);
        }
        __syncthreads();
#pragma unroll
        for (int k = 0; k < 32; ++k) {
            float4 a  = *(const float4*)&As[k][ty << 2];
            float4 bv = *(const float4*)&Bs[k][tx << 2];
            float am[4] = {a.x, a.y, a.z, a.w};
            float bn[4] = {bv.x, bv.y, bv.z, bv.w};
#pragma unroll
            for (int i = 0; i < 4; ++i)
#pragma unroll
                for (int j = 0; j < 4; ++j)
                    acc[i][j] = fmaf(am[i], bn[j], acc[i][j]);
        }
        __syncthreads();
    }
#pragma unroll
    for (int i = 0; i < 4; ++i) {
        int row = b * 64 + (ty << 2) + i;
        float4 o;
        o.x = acc[i][0]; o.y = acc[i][1]; o.z = acc[i][2]; o.w = acc[i][3];
        *(float4*)(pt + ((size_t)kt * 256 + row) * DIM + nb + (tx << 2)) = o;
    }
}

// out = sum_{kt=0..7} pt[kt]. 32768 float4s, grid 128 x 256.
__global__ __launch_bounds__(256) void reduce_kernel(
    const float* __restrict__ pt, float* __restrict__ out)
{
    int idx = blockIdx.x * 256 + threadIdx.x;
    const float4* p = (const float4*)pt;
    float4 a = p[idx];
#pragma unroll
    for (int k = 1; k < 8; ++k) {
        float4 v = p[k * 32768 + idx];
        a.x += v.x; a.y += v.y; a.z += v.z; a.w += v.w;
    }
    ((float4*)out)[idx] = a;
}

extern "C" void kernel_launch(void* const* d_in, const int* in_sizes, int n_in,
                              void* d_out, int out_size, void* d_ws, size_t ws_size,
                              hipStream_t stream) {
    const float* queries = (const float*)d_in[0];
    const float* keys    = (const float*)d_in[1];
    const float* values  = (const float*)d_in[2];
    const float* W1      = (const float*)d_in[3];
    const float* b1      = (const float*)d_in[4];
    const float* w2      = (const float*)d_in[5];
    float* out = (float*)d_out;

    float* qp = (float*)d_ws;                       // 256*512 f32
    float* kp = qp + 256 * 512;                     // 4096*512 f32
    float* sc = kp + 4096 * 512;                    // 2 x 256*1024 f32
    float* at = sc + 2 * 256 * 1024;                // 256*1024 f32
    float* pt = at + 256 * 1024;                    // 8 x 256*512 f32
    unsigned short* qbf = (unsigned short*)(pt + 8 * 256 * 512);
    unsigned short* kbf = qbf + 256 * 512;
    unsigned short* wbf = kbf + 4096 * 512;
    (void)in_sizes; (void)n_in; (void)ws_size; (void)out_size;

    convert_bf16<<<dim3(2688), 256, 0, stream>>>(queries, keys, W1, qbf, kbf, wbf);
    proj_mfma<<<dim3(544), 256, 0, stream>>>(qbf, kbf, wbf, b1, qp, kp);
    scores_kernel<<<dim3(32, 8, 4), 256, 0, stream>>>(qp, kp, w2, sc);
    softmax_kernel<<<dim3(256), 256, 0, stream>>>(sc, at);
    av_gemm<<<dim3(8, 8, 4), 256, 0, stream>>>(at, values, pt);
    reduce_kernel<<<dim3(128), 256, 0, stream>>>(pt, out);
}